// Round 22
// baseline (50.635 us; speedup 1.0000x reference)
//
#include <hip/hip_runtime.h>
#include <stdint.h>

#define SEQ 4096
#define DM 768
#define DH 64

typedef __attribute__((ext_vector_type(8))) short short8;   // 8 x bf16 (4 VGPR) MFMA frag
typedef __attribute__((ext_vector_type(4))) short short4v;  // 8B LDS store
typedef __attribute__((ext_vector_type(4))) float f32x4;    // MFMA accumulator
typedef __attribute__((ext_vector_type(2))) uint32_t uint2v; // 8B packed bf16x4

#define LOG2E 1.4426950408889634f

// round-to-nearest-even f32 -> bf16 (bit pattern in low 16)
static __device__ __forceinline__ short bf16r(float f) {
  union { float f; uint32_t u; } v; v.f = f;
  uint32_t u = v.u;
  return (short)((u + 0x7FFFu + ((u >> 16) & 1u)) >> 16);
}

static __device__ __forceinline__ float bf16f(uint16_t u) {
  union { uint32_t u; float f; } v; v.u = ((uint32_t)u) << 16;
  return v.f;
}

// pack two f32 -> bf16x2 in one VALU op (RNE, same rounding as bf16r)
static __device__ __forceinline__ uint32_t cvtpk(float a, float b) {
  uint32_t r;
  asm("v_cvt_pk_bf16_f32 %0, %1, %2" : "=v"(r) : "v"(a), "v"(b));
  return r;
}

// XOR-swizzled byte offset in a 128B-row LDS tile (kills stride-128B bank conflicts, G4)
static __device__ __forceinline__ int swz(int row, int b) {
  return row * 128 + (b ^ ((row & 7) << 4));
}

// P redistribution: lane-local P dwords -> PV B-fragment via ds_bpermute (R18-verified)
static __device__ __forceinline__ void redist(const uint32_t* pk, int bp0, int bp1,
                                              bool hi2, short8& pa0s, short8& pa1s) {
  union { uint32_t d[4]; short8 s; } pa0u, pa1u;
  uint32_t x0 = __builtin_amdgcn_ds_bpermute(bp0, (int)pk[0]);
  uint32_t x2 = __builtin_amdgcn_ds_bpermute(bp0, (int)pk[2]);
  pa0u.d[0] = hi2 ? x2 : x0;
  uint32_t y1 = __builtin_amdgcn_ds_bpermute(bp0, (int)pk[1]);
  uint32_t y3 = __builtin_amdgcn_ds_bpermute(bp0, (int)pk[3]);
  pa0u.d[1] = hi2 ? y3 : y1;
  uint32_t z0 = __builtin_amdgcn_ds_bpermute(bp1, (int)pk[0]);
  uint32_t z2 = __builtin_amdgcn_ds_bpermute(bp1, (int)pk[2]);
  pa0u.d[2] = hi2 ? z2 : z0;
  uint32_t w1 = __builtin_amdgcn_ds_bpermute(bp1, (int)pk[1]);
  uint32_t w3 = __builtin_amdgcn_ds_bpermute(bp1, (int)pk[3]);
  pa0u.d[3] = hi2 ? w3 : w1;
  uint32_t x4 = __builtin_amdgcn_ds_bpermute(bp0, (int)pk[4]);
  uint32_t x6 = __builtin_amdgcn_ds_bpermute(bp0, (int)pk[6]);
  pa1u.d[0] = hi2 ? x6 : x4;
  uint32_t y5 = __builtin_amdgcn_ds_bpermute(bp0, (int)pk[5]);
  uint32_t y7 = __builtin_amdgcn_ds_bpermute(bp0, (int)pk[7]);
  pa1u.d[1] = hi2 ? y7 : y5;
  uint32_t z4 = __builtin_amdgcn_ds_bpermute(bp1, (int)pk[4]);
  uint32_t z6 = __builtin_amdgcn_ds_bpermute(bp1, (int)pk[6]);
  pa1u.d[2] = hi2 ? z6 : z4;
  uint32_t w5 = __builtin_amdgcn_ds_bpermute(bp1, (int)pk[5]);
  uint32_t w7 = __builtin_amdgcn_ds_bpermute(bp1, (int)pk[7]);
  pa1u.d[3] = hi2 ? w7 : w5;
  pa0s = pa0u.s;
  pa1s = pa1u.s;
}

// ---------------- K1: fused convert + QKV projection (R21, unchanged) -------------------
__global__ __launch_bounds__(256) void qkv_proj(
    const float* __restrict__ x, const float* __restrict__ Wq,
    const float* __restrict__ Wk, const float* __restrict__ Wv,
    uint16_t* __restrict__ qg, uint16_t* __restrict__ kg, uint16_t* __restrict__ vg) {
  __shared__ char smem[49152] __attribute__((aligned(16)));
  const int tid = threadIdx.x;
  const int lane = tid & 63, wv = tid >> 6;
  const int l15 = lane & 15, l4 = lane >> 4;
  const int row0 = blockIdx.x * 32;
  const int nh = blockIdx.y;

  const int xr = tid >> 4, xc4 = tid & 15;   // x: rows xr, xr+16; 16B col group xc4
  const int mh = wv & 1, ng = wv >> 1;       // M half, N group (3 tiles)
  const int wr0 = tid >> 3, wb16 = tid & 7;  // W: rows wr0 + i*32, col group wb16 (8 f32)

  const float* xp0 = x + (size_t)(row0 + xr) * DM + xc4 * 4;
  const float* xp1 = x + (size_t)(row0 + 16 + xr) * DM + xc4 * 4;

  const float* wp[3];
  int wlds[3];
  #pragma unroll
  for (int i = 0; i < 3; ++i) {
    int grow = nh * 96 + wr0 + i * 32;       // global row 0..191
    wp[i] = (grow < 64) ? (Wq + (size_t)grow * DM)
          : (grow < 128) ? (Wk + (size_t)(grow - 64) * DM)
                         : (Wv + (size_t)(grow - 128) * DM);
    wlds[i] = 4096 + swz(wr0 + i * 32, wb16 * 16);
  }
  const int xlds0 = swz(xr, xc4 * 8), xlds1 = swz(xr + 16, xc4 * 8);

  f32x4 acc[3];
  #pragma unroll
  for (int j = 0; j < 3; ++j) acc[j] = (f32x4){0.f, 0.f, 0.f, 0.f};

  float4 xA0, xA1, xB0, xB1;
  float4 wA[3][2], wB[3][2];

#define ISSUE_A(K0)                                                              \
  { xA0 = *(const float4*)(xp0 + (K0)); xA1 = *(const float4*)(xp1 + (K0));      \
    _Pragma("unroll")                                                            \
    for (int i = 0; i < 3; ++i) {                                                \
      wA[i][0] = *(const float4*)(wp[i] + (K0) + wb16 * 8);                      \
      wA[i][1] = *(const float4*)(wp[i] + (K0) + wb16 * 8 + 4);                  \
    }                                                                            \
    __builtin_amdgcn_sched_barrier(0); }
#define ISSUE_B(K0)                                                              \
  { xB0 = *(const float4*)(xp0 + (K0)); xB1 = *(const float4*)(xp1 + (K0));      \
    _Pragma("unroll")                                                            \
    for (int i = 0; i < 3; ++i) {                                                \
      wB[i][0] = *(const float4*)(wp[i] + (K0) + wb16 * 8);                      \
      wB[i][1] = *(const float4*)(wp[i] + (K0) + wb16 * 8 + 4);                  \
    }                                                                            \
    __builtin_amdgcn_sched_barrier(0); }
#define WRITE_SET(X0, X1, WS, BUF)                                               \
  { char* base_ = smem + (BUF) * 16384;                                          \
    uint2v p0 = { cvtpk(X0.x, X0.y), cvtpk(X0.z, X0.w) };                        \
    *(uint2v*)(base_ + xlds0) = p0;                                              \
    uint2v p1 = { cvtpk(X1.x, X1.y), cvtpk(X1.z, X1.w) };                        \
    *(uint2v*)(base_ + xlds1) = p1;                                              \
    _Pragma("unroll")                                                            \
    for (int i = 0; i < 3; ++i) {                                                \
      union { uint32_t u[4]; short8 s; } pk;                                     \
      pk.u[0] = cvtpk(WS[i][0].x, WS[i][0].y);                                   \
      pk.u[1] = cvtpk(WS[i][0].z, WS[i][0].w);                                   \
      pk.u[2] = cvtpk(WS[i][1].x, WS[i][1].y);                                   \
      pk.u[3] = cvtpk(WS[i][1].z, WS[i][1].w);                                   \
      *(short8*)(base_ + wlds[i]) = pk.s;                                        \
    } }
#define COMPUTE(BUF)                                                             \
  { char* base_ = smem + (BUF) * 16384;                                          \
    _Pragma("unroll")                                                            \
    for (int kc = 0; kc < 2; ++kc) {                                             \
      short8 af = *(const short8*)(base_ + swz(mh * 16 + l15, kc * 64 + l4 * 16)); \
      _Pragma("unroll")                                                          \
      for (int j = 0; j < 3; ++j) {                                              \
        int tl = ng * 3 + j;                                                     \
        short8 bfv = *(const short8*)(base_ + 4096 +                             \
                                      swz(tl * 16 + l15, kc * 64 + l4 * 16));    \
        acc[j] = __builtin_amdgcn_mfma_f32_16x16x32_bf16(af, bfv, acc[j], 0, 0, 0); \
      }                                                                          \
    } }
#define QSTEP(T, IS, X0, X1, WS, BUFW)                                           \
  { asm volatile("s_waitcnt lgkmcnt(0)" ::: "memory");                           \
    __builtin_amdgcn_s_barrier();                                                \
    if ((T) < 10) { IS(((T) + 2) * 64); }                                        \
    COMPUTE((T) % 3);                                                            \
    if ((T) < 11) { WRITE_SET(X0, X1, WS, (BUFW)); } }

  ISSUE_A(0);
  ISSUE_B(64);
  WRITE_SET(xA0, xA1, wA, 0);

  QSTEP(0,  ISSUE_A, xB0, xB1, wB, 1);
  QSTEP(1,  ISSUE_B, xA0, xA1, wA, 2);
  QSTEP(2,  ISSUE_A, xB0, xB1, wB, 0);
  QSTEP(3,  ISSUE_B, xA0, xA1, wA, 1);
  QSTEP(4,  ISSUE_A, xB0, xB1, wB, 2);
  QSTEP(5,  ISSUE_B, xA0, xA1, wA, 0);
  QSTEP(6,  ISSUE_A, xB0, xB1, wB, 1);
  QSTEP(7,  ISSUE_B, xA0, xA1, wA, 2);
  QSTEP(8,  ISSUE_A, xB0, xB1, wB, 0);
  QSTEP(9,  ISSUE_B, xA0, xA1, wA, 1);
  QSTEP(10, ISSUE_A, xB0, xB1, wB, 2);
  QSTEP(11, ISSUE_B, xA0, xA1, wA, 0);
#undef ISSUE_A
#undef ISSUE_B
#undef WRITE_SET
#undef COMPUTE
#undef QSTEP

  #pragma unroll
  for (int j = 0; j < 3; ++j) {
    int NT = nh * 6 + ng * 3 + j;
    uint16_t* dst = (NT < 4) ? qg : (NT < 8) ? kg : vg;
    const float sc = (NT < 4) ? (0.125f * LOG2E) : 1.0f;
    int cb = (NT & 3) * 16 + l15;
    #pragma unroll
    for (int r = 0; r < 4; ++r) {
      int row = row0 + mh * 16 + l4 * 4 + r;
      dst[(size_t)row * DH + cb] = (uint16_t)bf16r(acc[j][r] * sc);
    }
  }
}

// ---------------- K2: causal flash attention, QBLK=128, split-KV, S^T -------------------
// Each wave owns TWO 16-row q-subtiles (A: rows q0+wv*16.., B: +64). One K/V staging
// serves 128 q rows (half the traffic, half the blocks vs QBLK=64), and the two
// independent softmax/bpermute chains per wave overlap each other's stalls.
// A-subtile tiles beyond its causal limit are fully masked (exp->0, Ml slot unread).
__global__ __launch_bounds__(256) void attn_split(
    const uint16_t* __restrict__ qg, const uint16_t* __restrict__ kg,
    const uint16_t* __restrict__ vg, uint16_t* __restrict__ zg,
    uint16_t* __restrict__ Opart, float* __restrict__ Ml, int CHUNK, int MAXCH) {
  __shared__ char smem[32768] __attribute__((aligned(16)));
  // buffers: K0 @0, V0 @8192, K1 @16384, V1 @24576

  const int tid = threadIdx.x;
  const int lane = tid & 63, wv = tid >> 6;
  const int l15 = lane & 15, l4 = lane >> 4;
  const int qt = blockIdx.x, ch = blockIdx.y, b = blockIdx.z;
  const int q0 = qt << 7;                     // 128-row q block
  const int kv_lim = q0 + 128;
  const int kv_begin = ch * CHUNK;
  if (kv_begin >= kv_lim) return;             // empty chunk (causal triangle)
  const int kv_end = min(kv_begin + CHUNK, kv_lim);
  const int ntiles = (kv_end - kv_begin) >> 6;

  const uint16_t* qb = qg + (size_t)b * SEQ * DH;
  const uint16_t* kb = kg + (size_t)b * SEQ * DH;
  const uint16_t* vb = vg + (size_t)b * SEQ * DH;

  const int qrowA = q0 + wv * 16 + l15;
  const int qrowB = qrowA + 64;
  short8 qfA0 = *(const short8*)(qb + (size_t)qrowA * DH + l4 * 8);
  short8 qfA1 = *(const short8*)(qb + (size_t)qrowA * DH + 32 + l4 * 8);
  short8 qfB0 = *(const short8*)(qb + (size_t)qrowB * DH + l4 * 8);
  short8 qfB1 = *(const short8*)(qb + (size_t)qrowB * DH + 32 + l4 * 8);

  int koffA[4], koffB[4], voffA[4], voffB[4];
  #pragma unroll
  for (int n = 0; n < 4; ++n) {
    koffA[n] = swz(n * 16 + l15, l4 * 16);
    koffB[n] = swz(n * 16 + l15, 64 + l4 * 16);
    int dr = n * 16 + l15;
    voffA[n] = 8192 + dr * 128 + ((l4 * 16) ^ ((dr & 7) << 4));
    voffB[n] = 8192 + dr * 128 + ((64 + l4 * 16) ^ ((dr & 7) << 4));
  }

  const int ku = tid - 128;                     // K stagers (tid>=128)
  const int kvgV = tid >> 4, dqV = tid & 15;    // V stagers (tid<128)
  short8 sreg[4];
  short4v vr8[8];
  int soff[4], vwoff[4];
  if (tid >= 128) {
    #pragma unroll
    for (int i = 0; i < 4; ++i) {
      int c = ku + (i << 7);
      soff[i] = swz(c >> 3, (c & 7) * 16);
    }
  } else {
    #pragma unroll
    for (int c = 0; c < 4; ++c)
      vwoff[c] = 8192 + swz(dqV * 4 + c, kvgV * 16);
  }

#define LOAD_REGS(KV0)                                                               \
  if (tid >= 128) {                                                                  \
    _Pragma("unroll")                                                                \
    for (int i = 0; i < 4; ++i) {                                                    \
      int c = ku + (i << 7);                                                         \
      sreg[i] = *(const short8*)(kb + (size_t)((KV0) + (c >> 3)) * DH + (c & 7) * 8);  \
    }                                                                                \
  } else {                                                                           \
    _Pragma("unroll")                                                                \
    for (int i = 0; i < 8; ++i)                                                      \
      vr8[i] = *(const short4v*)(vb + (size_t)((KV0) + kvgV * 8 + i) * DH + dqV * 4);  \
  }

#define STAGE_WRITE(BUF)                                                             \
  {                                                                                  \
    char* base_ = smem + ((BUF) << 14);                                              \
    if (tid >= 128) {                                                                \
      _Pragma("unroll")                                                              \
      for (int i = 0; i < 4; ++i) *(short8*)(base_ + soff[i]) = sreg[i];             \
    } else {                                                                         \
      _Pragma("unroll")                                                              \
      for (int c = 0; c < 4; ++c) {                                                  \
        short8 w;                                                                    \
        _Pragma("unroll")                                                            \
        for (int i = 0; i < 8; ++i) w[i] = vr8[i][c];                                \
        *(short8*)(base_ + vwoff[c]) = w;                                            \
      }                                                                              \
    }                                                                                \
  }

  LOAD_REGS(kv_begin);
  STAGE_WRITE(0);

  f32x4 oaccA[4], oaccB[4];
  #pragma unroll
  for (int n = 0; n < 4; ++n) {
    oaccA[n] = (f32x4){0.f, 0.f, 0.f, 0.f};
    oaccB[n] = (f32x4){0.f, 0.f, 0.f, 0.f};
  }
  float lrunA = 0.f, lrunB = 0.f;

  const int bp0 = (((l4 & 1) << 5) + l15) << 2;
  const int bp1 = bp0 + 64;
  const bool hi2 = (l4 >> 1) != 0;

  for (int T = 0; T < ntiles; ++T) {
    const int kv0 = kv_begin + (T << 6);
    const bool more = (T + 1 < ntiles);
    if (more) { LOAD_REGS(kv0 + 64); }
    __syncthreads();  // publishes buf[T&1]
    char* cb_ = smem + ((T & 1) << 14);

    // S^T for both subtiles: 16 MFMA (independent A/B chains)
    f32x4 saccA[4], saccB[4];
    #pragma unroll
    for (int n = 0; n < 4; ++n) {
      saccA[n] = (f32x4){0.f, 0.f, 0.f, 0.f};
      saccB[n] = (f32x4){0.f, 0.f, 0.f, 0.f};
    }
    __builtin_amdgcn_s_setprio(1);
    #pragma unroll
    for (int n = 0; n < 4; ++n) {
      short8 kf0 = *(const short8*)(cb_ + koffA[n]);
      short8 kf1 = *(const short8*)(cb_ + koffB[n]);
      saccA[n] = __builtin_amdgcn_mfma_f32_16x16x32_bf16(kf0, qfA0, saccA[n], 0, 0, 0);
      saccA[n] = __builtin_amdgcn_mfma_f32_16x16x32_bf16(kf1, qfA1, saccA[n], 0, 0, 0);
      saccB[n] = __builtin_amdgcn_mfma_f32_16x16x32_bf16(kf0, qfB0, saccB[n], 0, 0, 0);
      saccB[n] = __builtin_amdgcn_mfma_f32_16x16x32_bf16(kf1, qfB1, saccB[n], 0, 0, 0);
    }
    __builtin_amdgcn_s_setprio(0);

    if (more) { STAGE_WRITE((T + 1) & 1); }

    // causal mask (tile may straddle either subtile's diagonal)
    if (kv0 + 63 > q0) {
      #pragma unroll
      for (int n = 0; n < 4; ++n) {
        #pragma unroll
        for (int r = 0; r < 4; ++r) {
          int kvg_ = kv0 + n * 16 + l4 * 4 + r;
          if (kvg_ > qrowA) saccA[n][r] = -1e30f;
          if (kvg_ > qrowB) saccB[n][r] = -1e30f;
        }
      }
    }

    // no-max softmax, both subtiles (independent VALU chains)
    float lsA = 0.f, lsB = 0.f;
    #pragma unroll
    for (int n = 0; n < 4; ++n) {
      #pragma unroll
      for (int r = 0; r < 4; ++r) {
        float pA = __builtin_amdgcn_exp2f(saccA[n][r]);
        float pB = __builtin_amdgcn_exp2f(saccB[n][r]);
        saccA[n][r] = pA;
        saccB[n][r] = pB;
        lsA += pA;
        lsB += pB;
      }
    }
    lsA += __shfl_xor(lsA, 16);
    lsA += __shfl_xor(lsA, 32);
    lsB += __shfl_xor(lsB, 16);
    lsB += __shfl_xor(lsB, 32);
    lrunA += lsA;
    lrunB += lsB;

    uint32_t pkA[8], pkB[8];
    #pragma unroll
    for (int n = 0; n < 4; ++n) {
      pkA[n * 2]     = cvtpk(saccA[n][0], saccA[n][1]);
      pkA[n * 2 + 1] = cvtpk(saccA[n][2], saccA[n][3]);
      pkB[n * 2]     = cvtpk(saccB[n][0], saccB[n][1]);
      pkB[n * 2 + 1] = cvtpk(saccB[n][2], saccB[n][3]);
    }
    short8 paA0, paA1, paB0, paB1;
    redist(pkA, bp0, bp1, hi2, paA0, paA1);
    redist(pkB, bp0, bp1, hi2, paB0, paB1);

    // O^T += V^T x P for both subtiles (16 MFMA)
    __builtin_amdgcn_s_setprio(1);
    #pragma unroll
    for (int n = 0; n < 4; ++n) {
      short8 vf0 = *(const short8*)(cb_ + voffA[n]);
      short8 vf1 = *(const short8*)(cb_ + voffB[n]);
      oaccA[n] = __builtin_amdgcn_mfma_f32_16x16x32_bf16(vf0, paA0, oaccA[n], 0, 0, 0);
      oaccA[n] = __builtin_amdgcn_mfma_f32_16x16x32_bf16(vf1, paA1, oaccA[n], 0, 0, 0);
      oaccB[n] = __builtin_amdgcn_mfma_f32_16x16x32_bf16(vf0, paB0, oaccB[n], 0, 0, 0);
      oaccB[n] = __builtin_amdgcn_mfma_f32_16x16x32_bf16(vf1, paB1, oaccB[n], 0, 0, 0);
    }
    __builtin_amdgcn_s_setprio(0);
  }
#undef LOAD_REGS
#undef STAGE_WRITE

  const int rl = wv * 16 + l15;  // local q row within each 64-row half
  if (MAXCH == 1) {
    float invA = 1.0f / lrunA, invB = 1.0f / lrunB;
    uint16_t* zb = zg + (size_t)b * SEQ * DH;
    #pragma unroll
    for (int n = 0; n < 4; ++n) {
      short4v pA = { bf16r(oaccA[n][0] * invA), bf16r(oaccA[n][1] * invA),
                     bf16r(oaccA[n][2] * invA), bf16r(oaccA[n][3] * invA) };
      *(short4v*)(zb + (size_t)(q0 + rl) * DH + n * 16 + l4 * 4) = pA;
      short4v pB = { bf16r(oaccB[n][0] * invB), bf16r(oaccB[n][1] * invB),
                     bf16r(oaccB[n][2] * invB), bf16r(oaccB[n][3] * invB) };
      *(short4v*)(zb + (size_t)(q0 + 64 + rl) * DH + n * 16 + l4 * 4) = pB;
    }
  } else {
    // slots keyed by 64-row tile: A -> 2*qt, B -> 2*qt+1 (out_proj combine unchanged)
    const size_t slotA = ((size_t)(b << 6) + (qt << 1)) * MAXCH + ch;
    const size_t slotB = slotA + MAXCH;
    uint16_t* opA = Opart + slotA * 4096;
    uint16_t* opB = Opart + slotB * 4096;
    #pragma unroll
    for (int n = 0; n < 4; ++n) {
      short4v pA = { bf16r(oaccA[n][0]), bf16r(oaccA[n][1]),
                     bf16r(oaccA[n][2]), bf16r(oaccA[n][3]) };
      *(short4v*)(opA + (size_t)rl * 64 + n * 16 + l4 * 4) = pA;
      short4v pB = { bf16r(oaccB[n][0]), bf16r(oaccB[n][1]),
                     bf16r(oaccB[n][2]), bf16r(oaccB[n][3]) };
      *(short4v*)(opB + (size_t)rl * 64 + n * 16 + l4 * 4) = pB;
    }
    if (l4 == 0) {
      Ml[slotA * 64 + rl] = lrunA;
      Ml[slotB * 64 + rl] = lrunB;
    }
  }
}

// ---------------- K3: fused combine + out_proj (R21, unchanged) -------------------------
__global__ __launch_bounds__(256) void out_proj(
    const uint16_t* __restrict__ Opart, const float* __restrict__ Ml,
    const uint16_t* __restrict__ zg, const float* __restrict__ Wo,
    float* __restrict__ out, int CHUNK, int MAXCH) {
  __shared__ char smem[4096 + 32768] __attribute__((aligned(16)));
  char* Zl = smem;           // [32][64] bf16, swizzled
  char* Wl = smem + 4096;    // [256 m][64 h] bf16, swizzled
  const int tid = threadIdx.x;
  const int lane = tid & 63, wv = tid >> 6;
  const int l15 = lane & 15, l4 = lane >> 4;
  const int row0 = blockIdx.x * 32;   // global row (0..8191), never crosses batch/q-tile
  const int col0 = blockIdx.y * 256;

  // stage Z: one (row, 8-col group) per thread; inline split-KV combine
  {
    const int r = tid >> 3, c0 = (tid & 7) << 3;
    if (MAXCH == 1) {
      short8 v = *(const short8*)(zg + (size_t)(row0 + r) * DH + c0);
      *(short8*)(Zl + swz(r, c0 * 2)) = v;
    } else {
      const int b = row0 >> 12;
      const int rlb = row0 & 4095;
      const int qt = rlb >> 6, q0 = qt << 6;
      const int row_local = (rlb & 63) + r;   // 0..63 within the q-tile
      const int nch = (q0 + 64 + CHUNK - 1) / CHUNK;
      const size_t sbase = ((size_t)(b << 6) + qt) * MAXCH;
      float a[8] = {0.f, 0.f, 0.f, 0.f, 0.f, 0.f, 0.f, 0.f};
      float wsum = 0.f;
      for (int ch = 0; ch < nch; ++ch) {
        const size_t s = sbase + ch;
        wsum += Ml[s * 64 + row_local];
        short8 v = *(const short8*)(Opart + s * 4096 + (size_t)row_local * 64 + c0);
        #pragma unroll
        for (int j = 0; j < 8; ++j) a[j] += bf16f((uint16_t)v[j]);
      }
      float inv = 1.0f / wsum;
      short8 pk;
      #pragma unroll
      for (int j = 0; j < 8; ++j) pk[j] = bf16r(a[j] * inv);
      *(short8*)(Zl + swz(r, c0 * 2)) = pk;
    }
  }
  // stage Wo chunk from fp32: 256 rows x 64 h = 4096 float4, 16/thread, cvtpk convert
  #pragma unroll
  for (int i = 0; i < 16; ++i) {
    int id = tid + (i << 8);
    int m = id >> 4, c4 = id & 15;
    float4 vw = *(const float4*)(Wo + (size_t)(col0 + m) * DH + c4 * 4);
    uint2v pk = { cvtpk(vw.x, vw.y), cvtpk(vw.z, vw.w) };
    *(uint2v*)(Wl + swz(m, c4 * 8)) = pk;
  }
  __syncthreads();

  const int mh = wv & 1, ng = wv >> 1;
  short8 af0 = *(const short8*)(Zl + swz(mh * 16 + l15, l4 * 16));
  short8 af1 = *(const short8*)(Zl + swz(mh * 16 + l15, 64 + l4 * 16));
  f32x4 acc[8];
  #pragma unroll
  for (int j = 0; j < 8; ++j) acc[j] = (f32x4){0.f, 0.f, 0.f, 0.f};
  #pragma unroll
  for (int j = 0; j < 8; ++j) {
    int nt = ng * 8 + j;
    short8 b0 = *(const short8*)(Wl + swz(nt * 16 + l15, l4 * 16));
    acc[j] = __builtin_amdgcn_mfma_f32_16x16x32_bf16(af0, b0, acc[j], 0, 0, 0);
    short8 b1 = *(const short8*)(Wl + swz(nt * 16 + l15, 64 + l4 * 16));
    acc[j] = __builtin_amdgcn_mfma_f32_16x16x32_bf16(af1, b1, acc[j], 0, 0, 0);
  }
  #pragma unroll
  for (int j = 0; j < 8; ++j) {
    int nt = ng * 8 + j;
    #pragma unroll
    for (int r = 0; r < 4; ++r) {
      int row = row0 + mh * 16 + l4 * 4 + r;
      int col = col0 + nt * 16 + l15;
      out[(size_t)row * DM + col] = acc[j][r];
    }
  }
}

extern "C" void kernel_launch(void* const* d_in, const int* in_sizes, int n_in,
                              void* d_out, int out_size, void* d_ws, size_t ws_size,
                              hipStream_t stream) {
  const float* x  = (const float*)d_in[0];
  // d_in[1] = mask: never read (causality derived from indices)
  const float* Wq = (const float*)d_in[2];
  const float* Wk = (const float*)d_in[3];
  const float* Wv = (const float*)d_in[4];
  const float* Wo = (const float*)d_in[5];
  float* out = (float*)d_out;

  const size_t N = (size_t)2 * SEQ * DH;  // 524288 elems = 1MB per bf16 array
  uint16_t* qg = (uint16_t*)d_ws;
  uint16_t* kg = qg + N;
  uint16_t* vg = kg + N;
  uint16_t* zg = vg + N;                  // only used if maxch==1
  uint16_t* Opart = zg + N;               // bf16 partials

  // split factor: CHUNK = SEQ/maxch; maxch=16 = measured sweet spot
  int maxch = 16;
  while (maxch > 1) {
    size_t slots = (size_t)2 * 64 * maxch;
    size_t need = 4 * N * 2 + slots * (4096 * 2 + 64 * 4);
    if (need <= ws_size) break;
    maxch >>= 1;
  }
  const int CHUNK = SEQ / maxch;
  float* Ml = (float*)(Opart + (size_t)2 * 64 * maxch * 4096);

  qkv_proj<<<dim3(256, 2), 256, 0, stream>>>(x, Wq, Wk, Wv, qg, kg, vg);
  attn_split<<<dim3(32, maxch, 2), 256, 0, stream>>>(qg, kg, vg, zg, Opart, Ml,
                                                     CHUNK, maxch);
  out_proj<<<dim3(256, 3), 256, 0, stream>>>(Opart, Ml, zg, Wo, out, CHUNK, maxch);
}

// Round 23
// 47.057 us; speedup vs baseline: 1.0760x; 1.0760x over previous
//
#include <hip/hip_runtime.h>
#include <stdint.h>

#define SEQ 4096
#define DM 768
#define DH 64

typedef __attribute__((ext_vector_type(8))) short short8;   // 8 x bf16 (4 VGPR) MFMA frag
typedef __attribute__((ext_vector_type(4))) short short4v;  // 8B LDS store
typedef __attribute__((ext_vector_type(4))) float f32x4;    // MFMA accumulator
typedef __attribute__((ext_vector_type(2))) uint32_t uint2v; // 8B packed bf16x4

#define LOG2E 1.4426950408889634f

// round-to-nearest-even f32 -> bf16 (bit pattern in low 16)
static __device__ __forceinline__ short bf16r(float f) {
  union { float f; uint32_t u; } v; v.f = f;
  uint32_t u = v.u;
  return (short)((u + 0x7FFFu + ((u >> 16) & 1u)) >> 16);
}

static __device__ __forceinline__ float bf16f(uint16_t u) {
  union { uint32_t u; float f; } v; v.u = ((uint32_t)u) << 16;
  return v.f;
}

// pack two f32 -> bf16x2 in one VALU op (RNE, same rounding as bf16r)
static __device__ __forceinline__ uint32_t cvtpk(float a, float b) {
  uint32_t r;
  asm("v_cvt_pk_bf16_f32 %0, %1, %2" : "=v"(r) : "v"(a), "v"(b));
  return r;
}

// XOR-swizzled byte offset in a 128B-row LDS tile (kills stride-128B bank conflicts, G4)
static __device__ __forceinline__ int swz(int row, int b) {
  return row * 128 + (b ^ ((row & 7) << 4));
}

// ---------------- K1: fused convert + QKV projection ------------------------------------
__global__ __launch_bounds__(256) void qkv_proj(
    const float* __restrict__ x, const float* __restrict__ Wq,
    const float* __restrict__ Wk, const float* __restrict__ Wv,
    uint16_t* __restrict__ qg, uint16_t* __restrict__ kg, uint16_t* __restrict__ vg) {
  __shared__ char smem[49152] __attribute__((aligned(16)));
  const int tid = threadIdx.x;
  const int lane = tid & 63, wv = tid >> 6;
  const int l15 = lane & 15, l4 = lane >> 4;
  const int row0 = blockIdx.x * 32;
  const int nh = blockIdx.y;

  const int xr = tid >> 4, xc4 = tid & 15;   // x: rows xr, xr+16; 16B col group xc4
  const int mh = wv & 1, ng = wv >> 1;       // M half, N group (3 tiles)
  const int wr0 = tid >> 3, wb16 = tid & 7;  // W: rows wr0 + i*32, col group wb16 (8 f32)

  const float* xp0 = x + (size_t)(row0 + xr) * DM + xc4 * 4;
  const float* xp1 = x + (size_t)(row0 + 16 + xr) * DM + xc4 * 4;

  const float* wp[3];
  int wlds[3];
  #pragma unroll
  for (int i = 0; i < 3; ++i) {
    int grow = nh * 96 + wr0 + i * 32;       // global row 0..191
    wp[i] = (grow < 64) ? (Wq + (size_t)grow * DM)
          : (grow < 128) ? (Wk + (size_t)(grow - 64) * DM)
                         : (Wv + (size_t)(grow - 128) * DM);
    wlds[i] = 4096 + swz(wr0 + i * 32, wb16 * 16);
  }
  const int xlds0 = swz(xr, xc4 * 8), xlds1 = swz(xr + 16, xc4 * 8);

  f32x4 acc[3];
  #pragma unroll
  for (int j = 0; j < 3; ++j) acc[j] = (f32x4){0.f, 0.f, 0.f, 0.f};

  float4 xA0, xA1, xB0, xB1;
  float4 wA[3][2], wB[3][2];

#define ISSUE_A(K0)                                                              \
  { xA0 = *(const float4*)(xp0 + (K0)); xA1 = *(const float4*)(xp1 + (K0));      \
    _Pragma("unroll")                                                            \
    for (int i = 0; i < 3; ++i) {                                                \
      wA[i][0] = *(const float4*)(wp[i] + (K0) + wb16 * 8);                      \
      wA[i][1] = *(const float4*)(wp[i] + (K0) + wb16 * 8 + 4);                  \
    }                                                                            \
    __builtin_amdgcn_sched_barrier(0); }
#define ISSUE_B(K0)                                                              \
  { xB0 = *(const float4*)(xp0 + (K0)); xB1 = *(const float4*)(xp1 + (K0));      \
    _Pragma("unroll")                                                            \
    for (int i = 0; i < 3; ++i) {                                                \
      wB[i][0] = *(const float4*)(wp[i] + (K0) + wb16 * 8);                      \
      wB[i][1] = *(const float4*)(wp[i] + (K0) + wb16 * 8 + 4);                  \
    }                                                                            \
    __builtin_amdgcn_sched_barrier(0); }
#define WRITE_SET(X0, X1, WS, BUF)                                               \
  { char* base_ = smem + (BUF) * 16384;                                          \
    uint2v p0 = { cvtpk(X0.x, X0.y), cvtpk(X0.z, X0.w) };                        \
    *(uint2v*)(base_ + xlds0) = p0;                                              \
    uint2v p1 = { cvtpk(X1.x, X1.y), cvtpk(X1.z, X1.w) };                        \
    *(uint2v*)(base_ + xlds1) = p1;                                              \
    _Pragma("unroll")                                                            \
    for (int i = 0; i < 3; ++i) {                                                \
      union { uint32_t u[4]; short8 s; } pk;                                     \
      pk.u[0] = cvtpk(WS[i][0].x, WS[i][0].y);                                   \
      pk.u[1] = cvtpk(WS[i][0].z, WS[i][0].w);                                   \
      pk.u[2] = cvtpk(WS[i][1].x, WS[i][1].y);                                   \
      pk.u[3] = cvtpk(WS[i][1].z, WS[i][1].w);                                   \
      *(short8*)(base_ + wlds[i]) = pk.s;                                        \
    } }
#define COMPUTE(BUF)                                                             \
  { char* base_ = smem + (BUF) * 16384;                                          \
    _Pragma("unroll")                                                            \
    for (int kc = 0; kc < 2; ++kc) {                                             \
      short8 af = *(const short8*)(base_ + swz(mh * 16 + l15, kc * 64 + l4 * 16)); \
      _Pragma("unroll")                                                          \
      for (int j = 0; j < 3; ++j) {                                              \
        int tl = ng * 3 + j;                                                     \
        short8 bfv = *(const short8*)(base_ + 4096 +                             \
                                      swz(tl * 16 + l15, kc * 64 + l4 * 16));    \
        acc[j] = __builtin_amdgcn_mfma_f32_16x16x32_bf16(af, bfv, acc[j], 0, 0, 0); \
      }                                                                          \
    } }
#define QSTEP(T, IS, X0, X1, WS, BUFW)                                           \
  { asm volatile("s_waitcnt lgkmcnt(0)" ::: "memory");                           \
    __builtin_amdgcn_s_barrier();                                                \
    if ((T) < 10) { IS(((T) + 2) * 64); }                                        \
    COMPUTE((T) % 3);                                                            \
    if ((T) < 11) { WRITE_SET(X0, X1, WS, (BUFW)); } }

  ISSUE_A(0);
  ISSUE_B(64);
  WRITE_SET(xA0, xA1, wA, 0);

  QSTEP(0,  ISSUE_A, xB0, xB1, wB, 1);
  QSTEP(1,  ISSUE_B, xA0, xA1, wA, 2);
  QSTEP(2,  ISSUE_A, xB0, xB1, wB, 0);
  QSTEP(3,  ISSUE_B, xA0, xA1, wA, 1);
  QSTEP(4,  ISSUE_A, xB0, xB1, wB, 2);
  QSTEP(5,  ISSUE_B, xA0, xA1, wA, 0);
  QSTEP(6,  ISSUE_A, xB0, xB1, wB, 1);
  QSTEP(7,  ISSUE_B, xA0, xA1, wA, 2);
  QSTEP(8,  ISSUE_A, xB0, xB1, wB, 0);
  QSTEP(9,  ISSUE_B, xA0, xA1, wA, 1);
  QSTEP(10, ISSUE_A, xB0, xB1, wB, 2);
  QSTEP(11, ISSUE_B, xA0, xA1, wA, 0);
#undef ISSUE_A
#undef ISSUE_B
#undef WRITE_SET
#undef COMPUTE
#undef QSTEP

  #pragma unroll
  for (int j = 0; j < 3; ++j) {
    int NT = nh * 6 + ng * 3 + j;
    uint16_t* dst = (NT < 4) ? qg : (NT < 8) ? kg : vg;
    const float sc = (NT < 4) ? (0.125f * LOG2E) : 1.0f;
    int cb = (NT & 3) * 16 + l15;
    #pragma unroll
    for (int r = 0; r < 4; ++r) {
      int row = row0 + mh * 16 + l4 * 4 + r;
      dst[(size_t)row * DH + cb] = (uint16_t)bf16r(acc[j][r] * sc);
    }
  }
}

// ---------------- K2: causal flash attention, split-KV, S^T, double-buffered LDS --------
__global__ __launch_bounds__(256) void attn_split(
    const uint16_t* __restrict__ qg, const uint16_t* __restrict__ kg,
    const uint16_t* __restrict__ vg, uint16_t* __restrict__ zg,
    uint16_t* __restrict__ Opart, float* __restrict__ Ml, int CHUNK, int MAXCH) {
  __shared__ char smem[32768] __attribute__((aligned(16)));
  // buffers: K0 @0, V0 @8192, K1 @16384, V1 @24576

  const int tid = threadIdx.x;
  const int lane = tid & 63, wv = tid >> 6;
  const int l15 = lane & 15, l4 = lane >> 4;
  const int qt = blockIdx.x, ch = blockIdx.y, b = blockIdx.z;
  const int q0 = qt << 6;
  const int kv_lim = q0 + 64;
  const int kv_begin = ch * CHUNK;
  if (kv_begin >= kv_lim) return;  // empty chunk (causal triangle)
  const int kv_end = min(kv_begin + CHUNK, kv_lim);
  const int ntiles = (kv_end - kv_begin) >> 6;

  const uint16_t* qb = qg + (size_t)b * SEQ * DH;
  const uint16_t* kb = kg + (size_t)b * SEQ * DH;
  const uint16_t* vb = vg + (size_t)b * SEQ * DH;

  const int qrow = q0 + wv * 16 + l15;
  short8 qf0 = *(const short8*)(qb + (size_t)qrow * DH + l4 * 8);
  short8 qf1 = *(const short8*)(qb + (size_t)qrow * DH + 32 + l4 * 8);

  int koffA[4], koffB[4], voffA[4], voffB[4];
  #pragma unroll
  for (int n = 0; n < 4; ++n) {
    koffA[n] = swz(n * 16 + l15, l4 * 16);
    koffB[n] = swz(n * 16 + l15, 64 + l4 * 16);
    int dr = n * 16 + l15;
    voffA[n] = 8192 + dr * 128 + ((l4 * 16) ^ ((dr & 7) << 4));
    voffB[n] = 8192 + dr * 128 + ((64 + l4 * 16) ^ ((dr & 7) << 4));
  }

  const int ku = tid - 128;                     // K stagers (tid>=128)
  const int kvgV = tid >> 4, dqV = tid & 15;    // V stagers (tid<128)
  short8 sreg[4];
  short4v vr8[8];
  int soff[4], vwoff[4];
  if (tid >= 128) {
    #pragma unroll
    for (int i = 0; i < 4; ++i) {
      int c = ku + (i << 7);
      soff[i] = swz(c >> 3, (c & 7) * 16);
    }
  } else {
    #pragma unroll
    for (int c = 0; c < 4; ++c)
      vwoff[c] = 8192 + swz(dqV * 4 + c, kvgV * 16);
  }

#define LOAD_REGS(KV0)                                                               \
  if (tid >= 128) {                                                                  \
    _Pragma("unroll")                                                                \
    for (int i = 0; i < 4; ++i) {                                                    \
      int c = ku + (i << 7);                                                         \
      sreg[i] = *(const short8*)(kb + (size_t)((KV0) + (c >> 3)) * DH + (c & 7) * 8);  \
    }                                                                                \
  } else {                                                                           \
    _Pragma("unroll")                                                                \
    for (int i = 0; i < 8; ++i)                                                      \
      vr8[i] = *(const short4v*)(vb + (size_t)((KV0) + kvgV * 8 + i) * DH + dqV * 4);  \
  }

#define STAGE_WRITE(BUF)                                                             \
  {                                                                                  \
    char* base_ = smem + ((BUF) << 14);                                              \
    if (tid >= 128) {                                                                \
      _Pragma("unroll")                                                              \
      for (int i = 0; i < 4; ++i) *(short8*)(base_ + soff[i]) = sreg[i];             \
    } else {                                                                         \
      _Pragma("unroll")                                                              \
      for (int c = 0; c < 4; ++c) {                                                  \
        short8 w;                                                                    \
        _Pragma("unroll")                                                            \
        for (int i = 0; i < 8; ++i) w[i] = vr8[i][c];                                \
        *(short8*)(base_ + vwoff[c]) = w;                                            \
      }                                                                              \
    }                                                                                \
  }

  LOAD_REGS(kv_begin);
  STAGE_WRITE(0);

  f32x4 oaccT[4];   // O^T: col=q (lane&15), row=d = n*16 + l4*4 + r
  #pragma unroll
  for (int n = 0; n < 4; ++n) oaccT[n] = (f32x4){0.f, 0.f, 0.f, 0.f};
  float lrun = 0.f;

  const int bp0 = (((l4 & 1) << 5) + l15) << 2;
  const int bp1 = bp0 + 64;
  const bool hi2 = (l4 >> 1) != 0;

  for (int T = 0; T < ntiles; ++T) {
    const int kv0 = kv_begin + (T << 6);
    const bool more = (T + 1 < ntiles);
    if (more) { LOAD_REGS(kv0 + 64); }
    __syncthreads();  // publishes buf[T&1]
    char* cb_ = smem + ((T & 1) << 14);

    f32x4 sacc[4];
    #pragma unroll
    for (int n = 0; n < 4; ++n) sacc[n] = (f32x4){0.f, 0.f, 0.f, 0.f};
    __builtin_amdgcn_s_setprio(1);
    #pragma unroll
    for (int n = 0; n < 4; ++n) {
      short8 kf0 = *(const short8*)(cb_ + koffA[n]);
      sacc[n] = __builtin_amdgcn_mfma_f32_16x16x32_bf16(kf0, qf0, sacc[n], 0, 0, 0);
      short8 kf1 = *(const short8*)(cb_ + koffB[n]);
      sacc[n] = __builtin_amdgcn_mfma_f32_16x16x32_bf16(kf1, qf1, sacc[n], 0, 0, 0);
    }
    __builtin_amdgcn_s_setprio(0);

    if (more) { STAGE_WRITE((T + 1) & 1); }

    if (kv0 + 63 > q0) {
      #pragma unroll
      for (int n = 0; n < 4; ++n) {
        #pragma unroll
        for (int r = 0; r < 4; ++r) {
          int kvg_ = kv0 + n * 16 + l4 * 4 + r;
          if (kvg_ > qrow) sacc[n][r] = -1e30f;
        }
      }
    }

    float ls = 0.f;
    #pragma unroll
    for (int n = 0; n < 4; ++n) {
      #pragma unroll
      for (int r = 0; r < 4; ++r) {
        float p = __builtin_amdgcn_exp2f(sacc[n][r]);
        sacc[n][r] = p;
        ls += p;
      }
    }
    ls += __shfl_xor(ls, 16);
    ls += __shfl_xor(ls, 32);
    lrun += ls;

    uint32_t pk[8];
    #pragma unroll
    for (int n = 0; n < 4; ++n) {
      pk[n * 2]     = cvtpk(sacc[n][0], sacc[n][1]);
      pk[n * 2 + 1] = cvtpk(sacc[n][2], sacc[n][3]);
    }
    union { uint32_t d[4]; short8 s; } pa0u, pa1u;
    {
      uint32_t x0 = __builtin_amdgcn_ds_bpermute(bp0, (int)pk[0]);
      uint32_t x2 = __builtin_amdgcn_ds_bpermute(bp0, (int)pk[2]);
      pa0u.d[0] = hi2 ? x2 : x0;
      uint32_t y1 = __builtin_amdgcn_ds_bpermute(bp0, (int)pk[1]);
      uint32_t y3 = __builtin_amdgcn_ds_bpermute(bp0, (int)pk[3]);
      pa0u.d[1] = hi2 ? y3 : y1;
      uint32_t z0 = __builtin_amdgcn_ds_bpermute(bp1, (int)pk[0]);
      uint32_t z2 = __builtin_amdgcn_ds_bpermute(bp1, (int)pk[2]);
      pa0u.d[2] = hi2 ? z2 : z0;
      uint32_t w1 = __builtin_amdgcn_ds_bpermute(bp1, (int)pk[1]);
      uint32_t w3 = __builtin_amdgcn_ds_bpermute(bp1, (int)pk[3]);
      pa0u.d[3] = hi2 ? w3 : w1;
      uint32_t x4 = __builtin_amdgcn_ds_bpermute(bp0, (int)pk[4]);
      uint32_t x6 = __builtin_amdgcn_ds_bpermute(bp0, (int)pk[6]);
      pa1u.d[0] = hi2 ? x6 : x4;
      uint32_t y5 = __builtin_amdgcn_ds_bpermute(bp0, (int)pk[5]);
      uint32_t y7 = __builtin_amdgcn_ds_bpermute(bp0, (int)pk[7]);
      pa1u.d[1] = hi2 ? y7 : y5;
      uint32_t z4 = __builtin_amdgcn_ds_bpermute(bp1, (int)pk[4]);
      uint32_t z6 = __builtin_amdgcn_ds_bpermute(bp1, (int)pk[6]);
      pa1u.d[2] = hi2 ? z6 : z4;
      uint32_t w5 = __builtin_amdgcn_ds_bpermute(bp1, (int)pk[5]);
      uint32_t w7 = __builtin_amdgcn_ds_bpermute(bp1, (int)pk[7]);
      pa1u.d[3] = hi2 ? w7 : w5;
    }
    __builtin_amdgcn_s_setprio(1);
    #pragma unroll
    for (int n = 0; n < 4; ++n) {
      short8 vf0 = *(const short8*)(cb_ + voffA[n]);
      oaccT[n] = __builtin_amdgcn_mfma_f32_16x16x32_bf16(vf0, pa0u.s, oaccT[n], 0, 0, 0);
      short8 vf1 = *(const short8*)(cb_ + voffB[n]);
      oaccT[n] = __builtin_amdgcn_mfma_f32_16x16x32_bf16(vf1, pa1u.s, oaccT[n], 0, 0, 0);
    }
    __builtin_amdgcn_s_setprio(0);
  }
#undef LOAD_REGS
#undef STAGE_WRITE

  const int rl = wv * 16 + l15;  // local q row
  if (MAXCH == 1) {
    float invl = 1.0f / lrun;
    uint16_t* zb = zg + (size_t)b * SEQ * DH;
    #pragma unroll
    for (int n = 0; n < 4; ++n) {
      short4v pkv = { bf16r(oaccT[n][0] * invl), bf16r(oaccT[n][1] * invl),
                      bf16r(oaccT[n][2] * invl), bf16r(oaccT[n][3] * invl) };
      *(short4v*)(zb + (size_t)(q0 + rl) * DH + n * 16 + l4 * 4) = pkv;
    }
  } else {
    const size_t slot = ((size_t)(b << 6) + qt) * MAXCH + ch;
    uint16_t* op = Opart + slot * 4096;
    #pragma unroll
    for (int n = 0; n < 4; ++n) {
      short4v pkv = { bf16r(oaccT[n][0]), bf16r(oaccT[n][1]),
                      bf16r(oaccT[n][2]), bf16r(oaccT[n][3]) };
      *(short4v*)(op + (size_t)rl * 64 + n * 16 + l4 * 4) = pkv;
    }
    if (l4 == 0) Ml[slot * 64 + rl] = lrun;
  }
}

// ---------------- K3: fused combine + out_proj (Wo converted fp32->bf16 in staging) -----
__global__ __launch_bounds__(256) void out_proj(
    const uint16_t* __restrict__ Opart, const float* __restrict__ Ml,
    const uint16_t* __restrict__ zg, const float* __restrict__ Wo,
    float* __restrict__ out, int CHUNK, int MAXCH) {
  __shared__ char smem[4096 + 32768] __attribute__((aligned(16)));
  char* Zl = smem;           // [32][64] bf16, swizzled
  char* Wl = smem + 4096;    // [256 m][64 h] bf16, swizzled
  const int tid = threadIdx.x;
  const int lane = tid & 63, wv = tid >> 6;
  const int l15 = lane & 15, l4 = lane >> 4;
  const int row0 = blockIdx.x * 32;   // global row (0..8191), never crosses batch/q-tile
  const int col0 = blockIdx.y * 256;

  // stage Z: one (row, 8-col group) per thread; inline split-KV combine
  {
    const int r = tid >> 3, c0 = (tid & 7) << 3;
    if (MAXCH == 1) {
      short8 v = *(const short8*)(zg + (size_t)(row0 + r) * DH + c0);
      *(short8*)(Zl + swz(r, c0 * 2)) = v;
    } else {
      const int b = row0 >> 12;
      const int rlb = row0 & 4095;
      const int qt = rlb >> 6, q0 = qt << 6;
      const int row_local = (rlb & 63) + r;   // 0..63 within the q-tile
      const int nch = (q0 + 64 + CHUNK - 1) / CHUNK;
      const size_t sbase = ((size_t)(b << 6) + qt) * MAXCH;
      float a[8] = {0.f, 0.f, 0.f, 0.f, 0.f, 0.f, 0.f, 0.f};
      float wsum = 0.f;
      for (int ch = 0; ch < nch; ++ch) {
        const size_t s = sbase + ch;
        wsum += Ml[s * 64 + row_local];
        short8 v = *(const short8*)(Opart + s * 4096 + (size_t)row_local * 64 + c0);
        #pragma unroll
        for (int j = 0; j < 8; ++j) a[j] += bf16f((uint16_t)v[j]);
      }
      float inv = 1.0f / wsum;
      short8 pk;
      #pragma unroll
      for (int j = 0; j < 8; ++j) pk[j] = bf16r(a[j] * inv);
      *(short8*)(Zl + swz(r, c0 * 2)) = pk;
    }
  }
  // stage Wo chunk from fp32: 256 rows x 64 h = 4096 float4, 16/thread, cvtpk convert
  #pragma unroll
  for (int i = 0; i < 16; ++i) {
    int id = tid + (i << 8);
    int m = id >> 4, c4 = id & 15;
    float4 vw = *(const float4*)(Wo + (size_t)(col0 + m) * DH + c4 * 4);
    uint2v pk = { cvtpk(vw.x, vw.y), cvtpk(vw.z, vw.w) };
    *(uint2v*)(Wl + swz(m, c4 * 8)) = pk;
  }
  __syncthreads();

  const int mh = wv & 1, ng = wv >> 1;
  short8 af0 = *(const short8*)(Zl + swz(mh * 16 + l15, l4 * 16));
  short8 af1 = *(const short8*)(Zl + swz(mh * 16 + l15, 64 + l4 * 16));
  f32x4 acc[8];
  #pragma unroll
  for (int j = 0; j < 8; ++j) acc[j] = (f32x4){0.f, 0.f, 0.f, 0.f};
  #pragma unroll
  for (int j = 0; j < 8; ++j) {
    int nt = ng * 8 + j;
    short8 b0 = *(const short8*)(Wl + swz(nt * 16 + l15, l4 * 16));
    acc[j] = __builtin_amdgcn_mfma_f32_16x16x32_bf16(af0, b0, acc[j], 0, 0, 0);
    short8 b1 = *(const short8*)(Wl + swz(nt * 16 + l15, 64 + l4 * 16));
    acc[j] = __builtin_amdgcn_mfma_f32_16x16x32_bf16(af1, b1, acc[j], 0, 0, 0);
  }
  #pragma unroll
  for (int j = 0; j < 8; ++j) {
    int nt = ng * 8 + j;
    #pragma unroll
    for (int r = 0; r < 4; ++r) {
      int row = row0 + mh * 16 + l4 * 4 + r;
      int col = col0 + nt * 16 + l15;
      out[(size_t)row * DM + col] = acc[j][r];
    }
  }
}

extern "C" void kernel_launch(void* const* d_in, const int* in_sizes, int n_in,
                              void* d_out, int out_size, void* d_ws, size_t ws_size,
                              hipStream_t stream) {
  const float* x  = (const float*)d_in[0];
  // d_in[1] = mask: never read (causality derived from indices)
  const float* Wq = (const float*)d_in[2];
  const float* Wk = (const float*)d_in[3];
  const float* Wv = (const float*)d_in[4];
  const float* Wo = (const float*)d_in[5];
  float* out = (float*)d_out;

  const size_t N = (size_t)2 * SEQ * DH;  // 524288 elems = 1MB per bf16 array
  uint16_t* qg = (uint16_t*)d_ws;
  uint16_t* kg = qg + N;
  uint16_t* vg = kg + N;
  uint16_t* zg = vg + N;                  // only used if maxch==1
  uint16_t* Opart = zg + N;               // bf16 partials

  // split factor probe: maxch=8 (CHUNK=512, <=8 tiles/block, ~576 non-empty blocks)
  int maxch = 8;
  while (maxch > 1) {
    size_t slots = (size_t)2 * 64 * maxch;
    size_t need = 4 * N * 2 + slots * (4096 * 2 + 64 * 4);
    if (need <= ws_size) break;
    maxch >>= 1;
  }
  const int CHUNK = SEQ / maxch;
  float* Ml = (float*)(Opart + (size_t)2 * 64 * maxch * 4096);

  qkv_proj<<<dim3(256, 2), 256, 0, stream>>>(x, Wq, Wk, Wv, qg, kg, vg);
  attn_split<<<dim3(64, maxch, 2), 256, 0, stream>>>(qg, kg, vg, zg, Opart, Ml,
                                                     CHUNK, maxch);
  out_proj<<<dim3(256, 3), 256, 0, stream>>>(Opart, Ml, zg, Wo, out, CHUNK, maxch);
}

// Round 24
// 46.642 us; speedup vs baseline: 1.0856x; 1.0089x over previous
//
#include <hip/hip_runtime.h>
#include <stdint.h>

#define SEQ 4096
#define DM 768
#define DH 64

typedef __attribute__((ext_vector_type(8))) short short8;   // 8 x bf16 (4 VGPR) MFMA frag
typedef __attribute__((ext_vector_type(4))) short short4v;  // 8B LDS store
typedef __attribute__((ext_vector_type(4))) float f32x4;    // MFMA accumulator
typedef __attribute__((ext_vector_type(2))) uint32_t uint2v; // 8B packed bf16x4

#define LOG2E 1.4426950408889634f

// round-to-nearest-even f32 -> bf16 (bit pattern in low 16)
static __device__ __forceinline__ short bf16r(float f) {
  union { float f; uint32_t u; } v; v.f = f;
  uint32_t u = v.u;
  return (short)((u + 0x7FFFu + ((u >> 16) & 1u)) >> 16);
}

static __device__ __forceinline__ float bf16f(uint16_t u) {
  union { uint32_t u; float f; } v; v.u = ((uint32_t)u) << 16;
  return v.f;
}

// pack two f32 -> bf16x2 in one VALU op (RNE, same rounding as bf16r)
static __device__ __forceinline__ uint32_t cvtpk(float a, float b) {
  uint32_t r;
  asm("v_cvt_pk_bf16_f32 %0, %1, %2" : "=v"(r) : "v"(a), "v"(b));
  return r;
}

// XOR-swizzled byte offset in a 128B-row LDS tile (kills stride-128B bank conflicts, G4)
static __device__ __forceinline__ int swz(int row, int b) {
  return row * 128 + (b ^ ((row & 7) << 4));
}

// ---------------- K1: fused convert + QKV projection (R21, unchanged) -------------------
__global__ __launch_bounds__(256) void qkv_proj(
    const float* __restrict__ x, const float* __restrict__ Wq,
    const float* __restrict__ Wk, const float* __restrict__ Wv,
    uint16_t* __restrict__ qg, uint16_t* __restrict__ kg, uint16_t* __restrict__ vg) {
  __shared__ char smem[49152] __attribute__((aligned(16)));
  const int tid = threadIdx.x;
  const int lane = tid & 63, wv = tid >> 6;
  const int l15 = lane & 15, l4 = lane >> 4;
  const int row0 = blockIdx.x * 32;
  const int nh = blockIdx.y;

  const int xr = tid >> 4, xc4 = tid & 15;   // x: rows xr, xr+16; 16B col group xc4
  const int mh = wv & 1, ng = wv >> 1;       // M half, N group (3 tiles)
  const int wr0 = tid >> 3, wb16 = tid & 7;  // W: rows wr0 + i*32, col group wb16 (8 f32)

  const float* xp0 = x + (size_t)(row0 + xr) * DM + xc4 * 4;
  const float* xp1 = x + (size_t)(row0 + 16 + xr) * DM + xc4 * 4;

  const float* wp[3];
  int wlds[3];
  #pragma unroll
  for (int i = 0; i < 3; ++i) {
    int grow = nh * 96 + wr0 + i * 32;       // global row 0..191
    wp[i] = (grow < 64) ? (Wq + (size_t)grow * DM)
          : (grow < 128) ? (Wk + (size_t)(grow - 64) * DM)
                         : (Wv + (size_t)(grow - 128) * DM);
    wlds[i] = 4096 + swz(wr0 + i * 32, wb16 * 16);
  }
  const int xlds0 = swz(xr, xc4 * 8), xlds1 = swz(xr + 16, xc4 * 8);

  f32x4 acc[3];
  #pragma unroll
  for (int j = 0; j < 3; ++j) acc[j] = (f32x4){0.f, 0.f, 0.f, 0.f};

  float4 xA0, xA1, xB0, xB1;
  float4 wA[3][2], wB[3][2];

#define ISSUE_A(K0)                                                              \
  { xA0 = *(const float4*)(xp0 + (K0)); xA1 = *(const float4*)(xp1 + (K0));      \
    _Pragma("unroll")                                                            \
    for (int i = 0; i < 3; ++i) {                                                \
      wA[i][0] = *(const float4*)(wp[i] + (K0) + wb16 * 8);                      \
      wA[i][1] = *(const float4*)(wp[i] + (K0) + wb16 * 8 + 4);                  \
    }                                                                            \
    __builtin_amdgcn_sched_barrier(0); }
#define ISSUE_B(K0)                                                              \
  { xB0 = *(const float4*)(xp0 + (K0)); xB1 = *(const float4*)(xp1 + (K0));      \
    _Pragma("unroll")                                                            \
    for (int i = 0; i < 3; ++i) {                                                \
      wB[i][0] = *(const float4*)(wp[i] + (K0) + wb16 * 8);                      \
      wB[i][1] = *(const float4*)(wp[i] + (K0) + wb16 * 8 + 4);                  \
    }                                                                            \
    __builtin_amdgcn_sched_barrier(0); }
#define WRITE_SET(X0, X1, WS, BUF)                                               \
  { char* base_ = smem + (BUF) * 16384;                                          \
    uint2v p0 = { cvtpk(X0.x, X0.y), cvtpk(X0.z, X0.w) };                        \
    *(uint2v*)(base_ + xlds0) = p0;                                              \
    uint2v p1 = { cvtpk(X1.x, X1.y), cvtpk(X1.z, X1.w) };                        \
    *(uint2v*)(base_ + xlds1) = p1;                                              \
    _Pragma("unroll")                                                            \
    for (int i = 0; i < 3; ++i) {                                                \
      union { uint32_t u[4]; short8 s; } pk;                                     \
      pk.u[0] = cvtpk(WS[i][0].x, WS[i][0].y);                                   \
      pk.u[1] = cvtpk(WS[i][0].z, WS[i][0].w);                                   \
      pk.u[2] = cvtpk(WS[i][1].x, WS[i][1].y);                                   \
      pk.u[3] = cvtpk(WS[i][1].z, WS[i][1].w);                                   \
      *(short8*)(base_ + wlds[i]) = pk.s;                                        \
    } }
#define COMPUTE(BUF)                                                             \
  { char* base_ = smem + (BUF) * 16384;                                          \
    _Pragma("unroll")                                                            \
    for (int kc = 0; kc < 2; ++kc) {                                             \
      short8 af = *(const short8*)(base_ + swz(mh * 16 + l15, kc * 64 + l4 * 16)); \
      _Pragma("unroll")                                                          \
      for (int j = 0; j < 3; ++j) {                                              \
        int tl = ng * 3 + j;                                                     \
        short8 bfv = *(const short8*)(base_ + 4096 +                             \
                                      swz(tl * 16 + l15, kc * 64 + l4 * 16));    \
        acc[j] = __builtin_amdgcn_mfma_f32_16x16x32_bf16(af, bfv, acc[j], 0, 0, 0); \
      }                                                                          \
    } }
#define QSTEP(T, IS, X0, X1, WS, BUFW)                                           \
  { asm volatile("s_waitcnt lgkmcnt(0)" ::: "memory");                           \
    __builtin_amdgcn_s_barrier();                                                \
    if ((T) < 10) { IS(((T) + 2) * 64); }                                        \
    COMPUTE((T) % 3);                                                            \
    if ((T) < 11) { WRITE_SET(X0, X1, WS, (BUFW)); } }

  ISSUE_A(0);
  ISSUE_B(64);
  WRITE_SET(xA0, xA1, wA, 0);

  QSTEP(0,  ISSUE_A, xB0, xB1, wB, 1);
  QSTEP(1,  ISSUE_B, xA0, xA1, wA, 2);
  QSTEP(2,  ISSUE_A, xB0, xB1, wB, 0);
  QSTEP(3,  ISSUE_B, xA0, xA1, wA, 1);
  QSTEP(4,  ISSUE_A, xB0, xB1, wB, 2);
  QSTEP(5,  ISSUE_B, xA0, xA1, wA, 0);
  QSTEP(6,  ISSUE_A, xB0, xB1, wB, 1);
  QSTEP(7,  ISSUE_B, xA0, xA1, wA, 2);
  QSTEP(8,  ISSUE_A, xB0, xB1, wB, 0);
  QSTEP(9,  ISSUE_B, xA0, xA1, wA, 1);
  QSTEP(10, ISSUE_A, xB0, xB1, wB, 2);
  QSTEP(11, ISSUE_B, xA0, xA1, wA, 0);
#undef ISSUE_A
#undef ISSUE_B
#undef WRITE_SET
#undef COMPUTE
#undef QSTEP

  #pragma unroll
  for (int j = 0; j < 3; ++j) {
    int NT = nh * 6 + ng * 3 + j;
    uint16_t* dst = (NT < 4) ? qg : (NT < 8) ? kg : vg;
    const float sc = (NT < 4) ? (0.125f * LOG2E) : 1.0f;
    int cb = (NT & 3) * 16 + l15;
    #pragma unroll
    for (int r = 0; r < 4; ++r) {
      int row = row0 + mh * 16 + l4 * 4 + r;
      dst[(size_t)row * DH + cb] = (uint16_t)bf16r(acc[j][r] * sc);
    }
  }
}

// ---------------- K2: causal flash attention, split-KV, SINGLE-buffer LDS ---------------
// 16KB LDS (K @0, V @8192) -> 8 blocks/CU co-resident (vs 5 at 32KB dbuf): trade one
// extra barrier per tile for ~2.7x more resident waves to hide the latency chains
// (R17 counters: all pipes idle, Occupancy 18%). Issue-early LOAD_REGS still hides HBM.
__global__ __launch_bounds__(256) void attn_split(
    const uint16_t* __restrict__ qg, const uint16_t* __restrict__ kg,
    const uint16_t* __restrict__ vg, uint16_t* __restrict__ zg,
    uint16_t* __restrict__ Opart, float* __restrict__ Ml, int CHUNK, int MAXCH) {
  __shared__ char smem[16384] __attribute__((aligned(16)));
  // K @0 (8KB), V^T @8192 (8KB)

  const int tid = threadIdx.x;
  const int lane = tid & 63, wv = tid >> 6;
  const int l15 = lane & 15, l4 = lane >> 4;
  const int qt = blockIdx.x, ch = blockIdx.y, b = blockIdx.z;
  const int q0 = qt << 6;
  const int kv_lim = q0 + 64;
  const int kv_begin = ch * CHUNK;
  if (kv_begin >= kv_lim) return;  // empty chunk (causal triangle)
  const int kv_end = min(kv_begin + CHUNK, kv_lim);
  const int ntiles = (kv_end - kv_begin) >> 6;

  const uint16_t* qb = qg + (size_t)b * SEQ * DH;
  const uint16_t* kb = kg + (size_t)b * SEQ * DH;
  const uint16_t* vb = vg + (size_t)b * SEQ * DH;

  const int qrow = q0 + wv * 16 + l15;
  short8 qf0 = *(const short8*)(qb + (size_t)qrow * DH + l4 * 8);
  short8 qf1 = *(const short8*)(qb + (size_t)qrow * DH + 32 + l4 * 8);

  int koffA[4], koffB[4], voffA[4], voffB[4];
  #pragma unroll
  for (int n = 0; n < 4; ++n) {
    koffA[n] = swz(n * 16 + l15, l4 * 16);
    koffB[n] = swz(n * 16 + l15, 64 + l4 * 16);
    int dr = n * 16 + l15;
    voffA[n] = 8192 + dr * 128 + ((l4 * 16) ^ ((dr & 7) << 4));
    voffB[n] = 8192 + dr * 128 + ((64 + l4 * 16) ^ ((dr & 7) << 4));
  }

  const int ku = tid - 128;                     // K stagers (tid>=128)
  const int kvgV = tid >> 4, dqV = tid & 15;    // V stagers (tid<128)
  short8 sreg[4];
  short4v vr8[8];
  int soff[4], vwoff[4];
  if (tid >= 128) {
    #pragma unroll
    for (int i = 0; i < 4; ++i) {
      int c = ku + (i << 7);
      soff[i] = swz(c >> 3, (c & 7) * 16);
    }
  } else {
    #pragma unroll
    for (int c = 0; c < 4; ++c)
      vwoff[c] = 8192 + swz(dqV * 4 + c, kvgV * 16);
  }

#define LOAD_REGS(KV0)                                                               \
  if (tid >= 128) {                                                                  \
    _Pragma("unroll")                                                                \
    for (int i = 0; i < 4; ++i) {                                                    \
      int c = ku + (i << 7);                                                         \
      sreg[i] = *(const short8*)(kb + (size_t)((KV0) + (c >> 3)) * DH + (c & 7) * 8);  \
    }                                                                                \
  } else {                                                                           \
    _Pragma("unroll")                                                                \
    for (int i = 0; i < 8; ++i)                                                      \
      vr8[i] = *(const short4v*)(vb + (size_t)((KV0) + kvgV * 8 + i) * DH + dqV * 4);  \
  }

#define STAGE_WRITE()                                                                \
  {                                                                                  \
    if (tid >= 128) {                                                                \
      _Pragma("unroll")                                                              \
      for (int i = 0; i < 4; ++i) *(short8*)(smem + soff[i]) = sreg[i];              \
    } else {                                                                         \
      _Pragma("unroll")                                                              \
      for (int c = 0; c < 4; ++c) {                                                  \
        short8 w;                                                                    \
        _Pragma("unroll")                                                            \
        for (int i = 0; i < 8; ++i) w[i] = vr8[i][c];                                \
        *(short4v*)(0) ; } } }  // placeholder never used

  // (macro above unused; explicit staging below for single-buffer clarity)
#undef STAGE_WRITE

  // prologue: stage tile 0
  LOAD_REGS(kv_begin);
  if (tid >= 128) {
    #pragma unroll
    for (int i = 0; i < 4; ++i) *(short8*)(smem + soff[i]) = sreg[i];
  } else {
    #pragma unroll
    for (int c = 0; c < 4; ++c) {
      short8 w;
      #pragma unroll
      for (int i = 0; i < 8; ++i) w[i] = vr8[i][c];
      *(short8*)(smem + vwoff[c]) = w;
    }
  }
  __syncthreads();   // publish tile 0

  f32x4 oaccT[4];   // O^T: col=q (lane&15), row=d = n*16 + l4*4 + r
  #pragma unroll
  for (int n = 0; n < 4; ++n) oaccT[n] = (f32x4){0.f, 0.f, 0.f, 0.f};
  float lrun = 0.f;

  const int bp0 = (((l4 & 1) << 5) + l15) << 2;
  const int bp1 = bp0 + 64;
  const bool hi2 = (l4 >> 1) != 0;

  for (int T = 0; T < ntiles; ++T) {
    const int kv0 = kv_begin + (T << 6);
    const bool more = (T + 1 < ntiles);
    // issue next tile's global loads (HBM latency hides under this tile's compute)
    if (more) { LOAD_REGS(kv0 + 64); }

    f32x4 sacc[4];
    #pragma unroll
    for (int n = 0; n < 4; ++n) sacc[n] = (f32x4){0.f, 0.f, 0.f, 0.f};
    __builtin_amdgcn_s_setprio(1);
    #pragma unroll
    for (int n = 0; n < 4; ++n) {
      short8 kf0 = *(const short8*)(smem + koffA[n]);
      sacc[n] = __builtin_amdgcn_mfma_f32_16x16x32_bf16(kf0, qf0, sacc[n], 0, 0, 0);
      short8 kf1 = *(const short8*)(smem + koffB[n]);
      sacc[n] = __builtin_amdgcn_mfma_f32_16x16x32_bf16(kf1, qf1, sacc[n], 0, 0, 0);
    }
    __builtin_amdgcn_s_setprio(0);

    if (kv0 + 63 > q0) {
      #pragma unroll
      for (int n = 0; n < 4; ++n) {
        #pragma unroll
        for (int r = 0; r < 4; ++r) {
          int kvg_ = kv0 + n * 16 + l4 * 4 + r;
          if (kvg_ > qrow) sacc[n][r] = -1e30f;
        }
      }
    }

    float ls = 0.f;
    #pragma unroll
    for (int n = 0; n < 4; ++n) {
      #pragma unroll
      for (int r = 0; r < 4; ++r) {
        float p = __builtin_amdgcn_exp2f(sacc[n][r]);
        sacc[n][r] = p;
        ls += p;
      }
    }
    ls += __shfl_xor(ls, 16);
    ls += __shfl_xor(ls, 32);
    lrun += ls;

    uint32_t pk[8];
    #pragma unroll
    for (int n = 0; n < 4; ++n) {
      pk[n * 2]     = cvtpk(sacc[n][0], sacc[n][1]);
      pk[n * 2 + 1] = cvtpk(sacc[n][2], sacc[n][3]);
    }
    union { uint32_t d[4]; short8 s; } pa0u, pa1u;
    {
      uint32_t x0 = __builtin_amdgcn_ds_bpermute(bp0, (int)pk[0]);
      uint32_t x2 = __builtin_amdgcn_ds_bpermute(bp0, (int)pk[2]);
      pa0u.d[0] = hi2 ? x2 : x0;
      uint32_t y1 = __builtin_amdgcn_ds_bpermute(bp0, (int)pk[1]);
      uint32_t y3 = __builtin_amdgcn_ds_bpermute(bp0, (int)pk[3]);
      pa0u.d[1] = hi2 ? y3 : y1;
      uint32_t z0 = __builtin_amdgcn_ds_bpermute(bp1, (int)pk[0]);
      uint32_t z2 = __builtin_amdgcn_ds_bpermute(bp1, (int)pk[2]);
      pa0u.d[2] = hi2 ? z2 : z0;
      uint32_t w1 = __builtin_amdgcn_ds_bpermute(bp1, (int)pk[1]);
      uint32_t w3 = __builtin_amdgcn_ds_bpermute(bp1, (int)pk[3]);
      pa0u.d[3] = hi2 ? w3 : w1;
      uint32_t x4 = __builtin_amdgcn_ds_bpermute(bp0, (int)pk[4]);
      uint32_t x6 = __builtin_amdgcn_ds_bpermute(bp0, (int)pk[6]);
      pa1u.d[0] = hi2 ? x6 : x4;
      uint32_t y5 = __builtin_amdgcn_ds_bpermute(bp0, (int)pk[5]);
      uint32_t y7 = __builtin_amdgcn_ds_bpermute(bp0, (int)pk[7]);
      pa1u.d[1] = hi2 ? y7 : y5;
      uint32_t z4 = __builtin_amdgcn_ds_bpermute(bp1, (int)pk[4]);
      uint32_t z6 = __builtin_amdgcn_ds_bpermute(bp1, (int)pk[6]);
      pa1u.d[2] = hi2 ? z6 : z4;
      uint32_t w5 = __builtin_amdgcn_ds_bpermute(bp1, (int)pk[5]);
      uint32_t w7 = __builtin_amdgcn_ds_bpermute(bp1, (int)pk[7]);
      pa1u.d[3] = hi2 ? w7 : w5;
    }
    __builtin_amdgcn_s_setprio(1);
    #pragma unroll
    for (int n = 0; n < 4; ++n) {
      short8 vf0 = *(const short8*)(smem + voffA[n]);
      oaccT[n] = __builtin_amdgcn_mfma_f32_16x16x32_bf16(vf0, pa0u.s, oaccT[n], 0, 0, 0);
      short8 vf1 = *(const short8*)(smem + voffB[n]);
      oaccT[n] = __builtin_amdgcn_mfma_f32_16x16x32_bf16(vf1, pa1u.s, oaccT[n], 0, 0, 0);
    }
    __builtin_amdgcn_s_setprio(0);

    // single-buffer rotation: all reads of this tile done -> overwrite, republish
    if (more) {
      __syncthreads();
      if (tid >= 128) {
        #pragma unroll
        for (int i = 0; i < 4; ++i) *(short8*)(smem + soff[i]) = sreg[i];
      } else {
        #pragma unroll
        for (int c = 0; c < 4; ++c) {
          short8 w;
          #pragma unroll
          for (int i = 0; i < 8; ++i) w[i] = vr8[i][c];
          *(short8*)(smem + vwoff[c]) = w;
        }
      }
      __syncthreads();
    }
  }
#undef LOAD_REGS

  const int rl = wv * 16 + l15;  // local q row
  if (MAXCH == 1) {
    float invl = 1.0f / lrun;
    uint16_t* zb = zg + (size_t)b * SEQ * DH;
    #pragma unroll
    for (int n = 0; n < 4; ++n) {
      short4v pkv = { bf16r(oaccT[n][0] * invl), bf16r(oaccT[n][1] * invl),
                      bf16r(oaccT[n][2] * invl), bf16r(oaccT[n][3] * invl) };
      *(short4v*)(zb + (size_t)(q0 + rl) * DH + n * 16 + l4 * 4) = pkv;
    }
  } else {
    const size_t slot = ((size_t)(b << 6) + qt) * MAXCH + ch;
    uint16_t* op = Opart + slot * 4096;
    #pragma unroll
    for (int n = 0; n < 4; ++n) {
      short4v pkv = { bf16r(oaccT[n][0]), bf16r(oaccT[n][1]),
                      bf16r(oaccT[n][2]), bf16r(oaccT[n][3]) };
      *(short4v*)(op + (size_t)rl * 64 + n * 16 + l4 * 4) = pkv;
    }
    if (l4 == 0) Ml[slot * 64 + rl] = lrun;
  }
}

// ---------------- K3: fused combine + out_proj (R21, unchanged) -------------------------
__global__ __launch_bounds__(256) void out_proj(
    const uint16_t* __restrict__ Opart, const float* __restrict__ Ml,
    const uint16_t* __restrict__ zg, const float* __restrict__ Wo,
    float* __restrict__ out, int CHUNK, int MAXCH) {
  __shared__ char smem[4096 + 32768] __attribute__((aligned(16)));
  char* Zl = smem;           // [32][64] bf16, swizzled
  char* Wl = smem + 4096;    // [256 m][64 h] bf16, swizzled
  const int tid = threadIdx.x;
  const int lane = tid & 63, wv = tid >> 6;
  const int l15 = lane & 15, l4 = lane >> 4;
  const int row0 = blockIdx.x * 32;   // global row (0..8191), never crosses batch/q-tile
  const int col0 = blockIdx.y * 256;

  // stage Z: one (row, 8-col group) per thread; inline split-KV combine
  {
    const int r = tid >> 3, c0 = (tid & 7) << 3;
    if (MAXCH == 1) {
      short8 v = *(const short8*)(zg + (size_t)(row0 + r) * DH + c0);
      *(short8*)(Zl + swz(r, c0 * 2)) = v;
    } else {
      const int b = row0 >> 12;
      const int rlb = row0 & 4095;
      const int qt = rlb >> 6, q0 = qt << 6;
      const int row_local = (rlb & 63) + r;   // 0..63 within the q-tile
      const int nch = (q0 + 64 + CHUNK - 1) / CHUNK;
      const size_t sbase = ((size_t)(b << 6) + qt) * MAXCH;
      float a[8] = {0.f, 0.f, 0.f, 0.f, 0.f, 0.f, 0.f, 0.f};
      float wsum = 0.f;
      for (int ch = 0; ch < nch; ++ch) {
        const size_t s = sbase + ch;
        wsum += Ml[s * 64 + row_local];
        short8 v = *(const short8*)(Opart + s * 4096 + (size_t)row_local * 64 + c0);
        #pragma unroll
        for (int j = 0; j < 8; ++j) a[j] += bf16f((uint16_t)v[j]);
      }
      float inv = 1.0f / wsum;
      short8 pk;
      #pragma unroll
      for (int j = 0; j < 8; ++j) pk[j] = bf16r(a[j] * inv);
      *(short8*)(Zl + swz(r, c0 * 2)) = pk;
    }
  }
  // stage Wo chunk from fp32: 256 rows x 64 h = 4096 float4, 16/thread, cvtpk convert
  #pragma unroll
  for (int i = 0; i < 16; ++i) {
    int id = tid + (i << 8);
    int m = id >> 4, c4 = id & 15;
    float4 vw = *(const float4*)(Wo + (size_t)(col0 + m) * DH + c4 * 4);
    uint2v pk = { cvtpk(vw.x, vw.y), cvtpk(vw.z, vw.w) };
    *(uint2v*)(Wl + swz(m, c4 * 8)) = pk;
  }
  __syncthreads();

  const int mh = wv & 1, ng = wv >> 1;
  short8 af0 = *(const short8*)(Zl + swz(mh * 16 + l15, l4 * 16));
  short8 af1 = *(const short8*)(Zl + swz(mh * 16 + l15, 64 + l4 * 16));
  f32x4 acc[8];
  #pragma unroll
  for (int j = 0; j < 8; ++j) acc[j] = (f32x4){0.f, 0.f, 0.f, 0.f};
  #pragma unroll
  for (int j = 0; j < 8; ++j) {
    int nt = ng * 8 + j;
    short8 b0 = *(const short8*)(Wl + swz(nt * 16 + l15, l4 * 16));
    acc[j] = __builtin_amdgcn_mfma_f32_16x16x32_bf16(af0, b0, acc[j], 0, 0, 0);
    short8 b1 = *(const short8*)(Wl + swz(nt * 16 + l15, 64 + l4 * 16));
    acc[j] = __builtin_amdgcn_mfma_f32_16x16x32_bf16(af1, b1, acc[j], 0, 0, 0);
  }
  #pragma unroll
  for (int j = 0; j < 8; ++j) {
    int nt = ng * 8 + j;
    #pragma unroll
    for (int r = 0; r < 4; ++r) {
      int row = row0 + mh * 16 + l4 * 4 + r;
      int col = col0 + nt * 16 + l15;
      out[(size_t)row * DM + col] = acc[j][r];
    }
  }
}

extern "C" void kernel_launch(void* const* d_in, const int* in_sizes, int n_in,
                              void* d_out, int out_size, void* d_ws, size_t ws_size,
                              hipStream_t stream) {
  const float* x  = (const float*)d_in[0];
  // d_in[1] = mask: never read (causality derived from indices)
  const float* Wq = (const float*)d_in[2];
  const float* Wk = (const float*)d_in[3];
  const float* Wv = (const float*)d_in[4];
  const float* Wo = (const float*)d_in[5];
  float* out = (float*)d_out;

  const size_t N = (size_t)2 * SEQ * DH;  // 524288 elems = 1MB per bf16 array
  uint16_t* qg = (uint16_t*)d_ws;
  uint16_t* kg = qg + N;
  uint16_t* vg = kg + N;
  uint16_t* zg = vg + N;                  // only used if maxch==1
  uint16_t* Opart = zg + N;               // bf16 partials

  // split factor: maxch=16 (measured sweet spot; 8 identical, 32 regressed)
  int maxch = 16;
  while (maxch > 1) {
    size_t slots = (size_t)2 * 64 * maxch;
    size_t need = 4 * N * 2 + slots * (4096 * 2 + 64 * 4);
    if (need <= ws_size) break;
    maxch >>= 1;
  }
  const int CHUNK = SEQ / maxch;
  float* Ml = (float*)(Opart + (size_t)2 * 64 * maxch * 4096);

  qkv_proj<<<dim3(256, 2), 256, 0, stream>>>(x, Wq, Wk, Wv, qg, kg, vg);
  attn_split<<<dim3(64, maxch, 2), 256, 0, stream>>>(qg, kg, vg, zg, Opart, Ml,
                                                     CHUNK, maxch);
  out_proj<<<dim3(256, 3), 256, 0, stream>>>(Opart, Ml, zg, Wo, out, CHUNK, maxch);
}